// Round 1
// baseline (4005.926 us; speedup 1.0000x reference)
//
#include <hip/hip_runtime.h>
#include <math.h>

#define NN 9
#define RR 128
#define FF 512
#define LL 2
#define GPB 4   // graphs per block (64 lanes per graph: 32 col-lanes x 2 k-halves)

__device__ __forceinline__ float4 ld4(const float* p) { return *reinterpret_cast<const float4*>(p); }
__device__ __forceinline__ void st4(float* p, const float4 v) { *reinterpret_cast<float4*>(p) = v; }
__device__ __forceinline__ void fma4(float4& d, const float a, const float4 w) {
    d.x = fmaf(a, w.x, d.x);
    d.y = fmaf(a, w.y, d.y);
    d.z = fmaf(a, w.z, d.z);
    d.w = fmaf(a, w.w, d.w);
}
// combine the two k-halves of a graph (lane ^ 32 within the 64-lane wave)
__device__ __forceinline__ void xadd32(float4& v) {
    v.x += __shfl_xor(v.x, 32);
    v.y += __shfl_xor(v.y, 32);
    v.z += __shfl_xor(v.z, 32);
    v.w += __shfl_xor(v.w, 32);
}

__global__ __launch_bounds__(256, 4)
void backbone_kernel(const float* __restrict__ graph,
                     const int*   __restrict__ op_idx,
                     const float* __restrict__ op_table,
                     const float* __restrict__ dev_embed,
                     const float* __restrict__ gcn_W,
                     const float* __restrict__ gcn_b,
                     const float* __restrict__ ln_g,
                     const float* __restrict__ ln_b,
                     const float* __restrict__ ffn_W1,
                     const float* __restrict__ ffn_b1,
                     const float* __restrict__ ffn_W2,
                     const float* __restrict__ ffn_b2,
                     const float* __restrict__ fc_w,
                     const float* __restrict__ fc_b,
                     float* __restrict__ out)
{
    __shared__ float sX[GPB][NN][RR];   // x  / h_ln
    __shared__ float sT[GPB][NN][RR];   // agg / ffn hidden chunk
    __shared__ float sNA[GPB][81];
    __shared__ float sD[GPB][NN];

    const int tid  = threadIdx.x;        // 0..255
    const int cg   = tid & 31;           // column group: owns cols 4*cg .. 4*cg+3
    const int half = (tid >> 5) & 1;     // k-half: 0 -> k in [0,64), 1 -> [64,128)
    const int ms   = tid >> 6;           // graph slot within block (0..3)
    const int c0   = cg * 4;
    const int k0   = half * 64;
    const int b0   = blockIdx.x * GPB;

    // ---- stage x = op_table[op_idx] + dev_embed ----
    {
        const int sc = tid & 127;        // column
        const int sg = tid >> 7;         // 0..1 -> stages graphs sg, sg+2
        const float dv = dev_embed[sc];
        #pragma unroll
        for (int gg = sg; gg < GPB; gg += 2) {
            #pragma unroll
            for (int j = 0; j < NN; ++j) {
                const int idx = op_idx[(b0 + gg) * NN + j];   // wave-uniform -> s_load
                sX[gg][j][sc] = op_table[idx * RR + sc] + dv;
            }
        }
    }

    // ---- degree rsqrt (self-loop included) ----
    if (tid < GPB * NN) {
        const int gg = tid / NN, i = tid - gg * NN;
        const float* gr = graph + (size_t)(b0 + gg) * 81 + i * NN;
        float s = 1.0f;
        #pragma unroll
        for (int j = 0; j < NN; ++j) s += gr[j];
        sD[gg][i] = rsqrtf(s);
    }
    __syncthreads();

    // ---- normalized adjacency ----
    for (int e = tid; e < GPB * 81; e += 256) {
        const int gg = e / 81, r = e - gg * 81;
        const int i = r / NN, j = r - i * NN;
        const float v = graph[(size_t)(b0 + gg) * 81 + r] + (i == j ? 1.0f : 0.0f);
        sNA[gg][r] = v * sD[gg][i] * sD[gg][j];
    }
    __syncthreads();

    float4 acc[NN];   // FFN output / final features

    for (int l = 0; l < LL; ++l) {
        const float* gw = gcn_W  + l * RR * RR;
        const float* gb = gcn_b  + l * RR;
        const float* lg = ln_g   + l * RR;
        const float* lb = ln_b   + l * RR;
        const float* w1 = ffn_W1 + l * RR * FF;
        const float* b1 = ffn_b1 + l * FF;
        const float* w2 = ffn_W2 + l * FF * RR;
        const float* b2 = ffn_b2 + l * RR;

        // ---- agg = norm_adj @ x  -> sT  (node rows split by half parity) ----
        {
            float4 xv[NN];
            #pragma unroll
            for (int j = 0; j < NN; ++j) xv[j] = ld4(&sX[ms][j][c0]);
            for (int i = half; i < NN; i += 2) {
                float4 a = make_float4(0.f, 0.f, 0.f, 0.f);
                #pragma unroll
                for (int j = 0; j < NN; ++j) fma4(a, sNA[ms][i * NN + j], xv[j]);
                st4(&sT[ms][i][c0], a);
            }
        }
        __syncthreads();

        // ---- h = agg @ gcn_W + gcn_b  (k-split across halves) ----
        float4 h[NN];
        {
            const float4 z4  = make_float4(0.f, 0.f, 0.f, 0.f);
            const float4 gbv = ld4(&gb[c0]);
            const float4 ini = half ? z4 : gbv;   // bias counted once
            #pragma unroll
            for (int i = 0; i < NN; ++i) h[i] = ini;
            #pragma unroll 2
            for (int kk = 0; kk < 64; kk += 4) {
                const float* wp = gw + (size_t)(k0 + kk) * RR + c0;
                const float4 wv0 = ld4(wp);
                const float4 wv1 = ld4(wp + RR);
                const float4 wv2 = ld4(wp + 2 * RR);
                const float4 wv3 = ld4(wp + 3 * RR);
                #pragma unroll
                for (int i = 0; i < NN; ++i) {
                    const float4 a = ld4(&sT[ms][i][k0 + kk]);   // broadcast per half
                    fma4(h[i], a.x, wv0); fma4(h[i], a.y, wv1);
                    fma4(h[i], a.z, wv2); fma4(h[i], a.w, wv3);
                }
            }
            #pragma unroll
            for (int i = 0; i < NN; ++i) xadd32(h[i]);   // combine k-halves
        }

        // ---- relu + layernorm (reduction across the 32 col-lanes; halves identical) ----
        {
            const float4 lgv = ld4(&lg[c0]);
            const float4 lbv = ld4(&lb[c0]);
            #pragma unroll
            for (int i = 0; i < NN; ++i) {
                float4 v = h[i];
                v.x = fmaxf(v.x, 0.f); v.y = fmaxf(v.y, 0.f);
                v.z = fmaxf(v.z, 0.f); v.w = fmaxf(v.w, 0.f);
                float s = v.x + v.y + v.z + v.w;
                float q = v.x*v.x + v.y*v.y + v.z*v.z + v.w*v.w;
                #pragma unroll
                for (int m = 1; m <= 16; m <<= 1) {
                    s += __shfl_xor(s, m);
                    q += __shfl_xor(q, m);
                }
                const float mu  = s * (1.f / RR);
                const float var = q * (1.f / RR) - mu * mu;
                const float rs  = rsqrtf(var + 1e-5f);
                v.x = (v.x - mu) * rs * lgv.x + lbv.x;
                v.y = (v.y - mu) * rs * lgv.y + lbv.y;
                v.z = (v.z - mu) * rs * lgv.z + lbv.z;
                v.w = (v.w - mu) * rs * lgv.w + lbv.w;
                h[i] = v;
            }
        }

        // h_ln -> sX (all step-a reads of sX completed before the post-agg barrier)
        for (int i = half; i < NN; i += 2) st4(&sX[ms][i][c0], h[i]);

        // residual init: acc = h_ln + ffn_b2 (half 0 only; half 1 holds partials)
        {
            const float4 b2v = ld4(&b2[c0]);
            #pragma unroll
            for (int i = 0; i < NN; ++i) {
                if (half) {
                    acc[i] = make_float4(0.f, 0.f, 0.f, 0.f);
                } else {
                    acc[i] = h[i];
                    acc[i].x += b2v.x; acc[i].y += b2v.y;
                    acc[i].z += b2v.z; acc[i].w += b2v.w;
                }
            }
        }
        __syncthreads();

        // ---- FFN: 4 passes over F=512 in 128-wide chunks, k-split ----
        for (int p = 0; p < 4; ++p) {
            const int f0 = p * RR + c0;
            float4 t[NN];
            {
                const float4 z4  = make_float4(0.f, 0.f, 0.f, 0.f);
                const float4 b1v = ld4(&b1[f0]);
                const float4 ini = half ? z4 : b1v;
                #pragma unroll
                for (int i = 0; i < NN; ++i) t[i] = ini;
            }
            #pragma unroll 2
            for (int kk = 0; kk < 64; kk += 4) {
                const float* wp = w1 + (size_t)(k0 + kk) * FF + f0;
                const float4 wv0 = ld4(wp);
                const float4 wv1 = ld4(wp + FF);
                const float4 wv2 = ld4(wp + 2 * FF);
                const float4 wv3 = ld4(wp + 3 * FF);
                #pragma unroll
                for (int i = 0; i < NN; ++i) {
                    const float4 a = ld4(&sX[ms][i][k0 + kk]);
                    fma4(t[i], a.x, wv0); fma4(t[i], a.y, wv1);
                    fma4(t[i], a.z, wv2); fma4(t[i], a.w, wv3);
                }
            }
            #pragma unroll
            for (int i = 0; i < NN; ++i) {
                xadd32(t[i]);   // full pre-activation
                t[i].x = fmaxf(t[i].x, 0.f); t[i].y = fmaxf(t[i].y, 0.f);
                t[i].z = fmaxf(t[i].z, 0.f); t[i].w = fmaxf(t[i].w, 0.f);
            }
            __syncthreads();   // prior consumers of sT are done
            for (int i = half; i < NN; i += 2) st4(&sT[ms][i][c0], t[i]);
            __syncthreads();
            #pragma unroll 2
            for (int kk = 0; kk < 64; kk += 4) {
                const float* wp = w2 + (size_t)(p * RR + k0 + kk) * RR + c0;
                const float4 wv0 = ld4(wp);
                const float4 wv1 = ld4(wp + RR);
                const float4 wv2 = ld4(wp + 2 * RR);
                const float4 wv3 = ld4(wp + 3 * RR);
                #pragma unroll
                for (int i = 0; i < NN; ++i) {
                    const float4 a = ld4(&sT[ms][i][k0 + kk]);
                    fma4(acc[i], a.x, wv0); fma4(acc[i], a.y, wv1);
                    fma4(acc[i], a.z, wv2); fma4(acc[i], a.w, wv3);
                }
            }
        }

        // combine k-halves of FFN output (+ residual held in half 0)
        #pragma unroll
        for (int i = 0; i < NN; ++i) xadd32(acc[i]);

        // new x for next layer
        if (l + 1 < LL) {
            for (int i = half; i < NN; i += 2) st4(&sX[ms][i][c0], acc[i]);
            __syncthreads();
        }
    }

    // ---- readout: mean over nodes, dot fc_w, sigmoid ----
    {
        const float4 fw = ld4(&fc_w[c0]);
        float4 pv = make_float4(0.f, 0.f, 0.f, 0.f);
        #pragma unroll
        for (int i = 0; i < NN; ++i) {
            pv.x += acc[i].x; pv.y += acc[i].y;
            pv.z += acc[i].z; pv.w += acc[i].w;
        }
        float part = (pv.x*fw.x + pv.y*fw.y + pv.z*fw.z + pv.w*fw.w) * (1.f / 9.f);
        #pragma unroll
        for (int m = 1; m <= 16; m <<= 1) part += __shfl_xor(part, m);
        if (cg == 0 && half == 0) {
            const float yv = part + fc_b[0];
            out[b0 + ms] = 1.f / (1.f + expf(-yv));
        }
    }
}

extern "C" void kernel_launch(void* const* d_in, const int* in_sizes, int n_in,
                              void* d_out, int out_size, void* d_ws, size_t ws_size,
                              hipStream_t stream) {
    const float* graph     = (const float*)d_in[0];
    const int*   op_idx    = (const int*)  d_in[1];
    const float* op_table  = (const float*)d_in[2];
    const float* dev_embed = (const float*)d_in[3];
    const float* gcn_W     = (const float*)d_in[4];
    const float* gcn_b     = (const float*)d_in[5];
    const float* ln_g      = (const float*)d_in[6];
    const float* ln_b      = (const float*)d_in[7];
    const float* ffn_W1    = (const float*)d_in[8];
    const float* ffn_b1    = (const float*)d_in[9];
    const float* ffn_W2    = (const float*)d_in[10];
    const float* ffn_b2    = (const float*)d_in[11];
    const float* fc_w      = (const float*)d_in[12];
    const float* fc_b      = (const float*)d_in[13];
    float* out = (float*)d_out;

    const int nB = in_sizes[0] / 81;          // 32768
    dim3 grid(nB / GPB), block(256);
    backbone_kernel<<<grid, block, 0, stream>>>(
        graph, op_idx, op_table, dev_embed, gcn_W, gcn_b, ln_g, ln_b,
        ffn_W1, ffn_b1, ffn_W2, ffn_b2, fc_w, fc_b, out);
}

// Round 2
// 2592.351 us; speedup vs baseline: 1.5453x; 1.5453x over previous
//
#include <hip/hip_runtime.h>
#include <math.h>

#define NN 9
#define RR 128
#define FF 512
#define LL 2
#define GPB 4   // graphs per block == waves per block (one 64-lane wave per graph)

__device__ __forceinline__ float4 ld4(const float* p) { return *reinterpret_cast<const float4*>(p); }
__device__ __forceinline__ void st4(float* p, const float4 v) { *reinterpret_cast<float4*>(p) = v; }
__device__ __forceinline__ void fma4(float4& d, const float a, const float4 w) {
    d.x = fmaf(a, w.x, d.x);
    d.y = fmaf(a, w.y, d.y);
    d.z = fmaf(a, w.z, d.z);
    d.w = fmaf(a, w.w, d.w);
}
// combine the two k-halves of a graph (lane ^ 32 within the 64-lane wave)
__device__ __forceinline__ void xadd32(float4& v) {
    v.x += __shfl_xor(v.x, 32);
    v.y += __shfl_xor(v.y, 32);
    v.z += __shfl_xor(v.z, 32);
    v.w += __shfl_xor(v.w, 32);
}
__device__ __forceinline__ void relu4(float4& v) {
    v.x = fmaxf(v.x, 0.f); v.y = fmaxf(v.y, 0.f);
    v.z = fmaxf(v.z, 0.f); v.w = fmaxf(v.w, 0.f);
}

__global__ __launch_bounds__(256, 4)
void backbone_kernel(const float* __restrict__ graph,
                     const int*   __restrict__ op_idx,
                     const float* __restrict__ op_table,
                     const float* __restrict__ dev_embed,
                     const float* __restrict__ gcn_W,
                     const float* __restrict__ gcn_b,
                     const float* __restrict__ ln_g,
                     const float* __restrict__ ln_b,
                     const float* __restrict__ ffn_W1,
                     const float* __restrict__ ffn_b1,
                     const float* __restrict__ ffn_W2,
                     const float* __restrict__ ffn_b2,
                     const float* __restrict__ fc_w,
                     const float* __restrict__ fc_b,
                     float* __restrict__ out)
{
    // One wave per graph slot: sX[ms]/sT[ms]/sNA[ms]/sD[ms] are wave-private.
    // No __syncthreads anywhere — in-wave LDS ordering (DS ops complete in
    // order within a wave; compiler inserts lgkmcnt waits) is sufficient.
    __shared__ float sX[GPB][NN][RR];   // x  / h_ln
    __shared__ float sT[GPB][NN][RR];   // agg / ffn hidden chunk
    __shared__ float sNA[GPB][81];
    __shared__ float sD[GPB][NN];

    const int tid  = threadIdx.x;        // 0..255
    const int lane = tid & 63;           // lane within wave
    const int cg   = tid & 31;           // column group: owns cols 4*cg .. 4*cg+3
    const int half = (tid >> 5) & 1;     // k-half: 0 -> k in [0,64), 1 -> [64,128)
    const int ms   = tid >> 6;           // wave index == graph slot (0..3)
    const int c0   = cg * 4;
    const int k0   = half * 64;
    const int g    = blockIdx.x * GPB + ms;

    // ---- per-wave staging: x = op_table[op_idx] + dev_embed ----
    {
        const float dv0 = dev_embed[lane];
        const float dv1 = dev_embed[lane + 64];
        #pragma unroll
        for (int j = 0; j < NN; ++j) {
            const int idx = op_idx[g * NN + j];          // wave-uniform -> s_load
            sX[ms][j][lane]      = op_table[idx * RR + lane]      + dv0;
            sX[ms][j][lane + 64] = op_table[idx * RR + lane + 64] + dv1;
        }
    }

    // ---- per-wave adjacency normalization (a_hat, rsqrt degrees, norm) ----
    {
        const float* gp = graph + (size_t)g * 81;
        {   // raw a_hat -> sNA (elements 0..63)
            const int i = lane / NN, j = lane - i * NN;
            sNA[ms][lane] = gp[lane] + (i == j ? 1.0f : 0.0f);
        }
        if (lane < 17) {  // elements 64..80
            const int e = lane + 64;
            const int i = e / NN, j = e - i * NN;
            sNA[ms][e] = gp[e] + (i == j ? 1.0f : 0.0f);
        }
        if (lane < NN) {  // row sums -> rsqrt
            float s = 0.f;
            #pragma unroll
            for (int j = 0; j < NN; ++j) s += sNA[ms][lane * NN + j];
            sD[ms][lane] = rsqrtf(s);
        }
        {   // normalize in place
            const int i = lane / NN, j = lane - i * NN;
            sNA[ms][lane] *= sD[ms][i] * sD[ms][j];
        }
        if (lane < 17) {
            const int e = lane + 64;
            const int i = e / NN, j = e - i * NN;
            sNA[ms][e] *= sD[ms][i] * sD[ms][j];
        }
    }

    float4 acc[NN];   // FFN output / final features (compile-time indexed ONLY)

    for (int l = 0; l < LL; ++l) {
        const float* gw = gcn_W  + l * RR * RR;
        const float* gb = gcn_b  + l * RR;
        const float* lg = ln_g   + l * RR;
        const float* lb = ln_b   + l * RR;
        const float* w1 = ffn_W1 + l * RR * FF;
        const float* b1 = ffn_b1 + l * FF;
        const float* w2 = ffn_W2 + l * FF * RR;
        const float* b2 = ffn_b2 + l * RR;

        // ---- agg = norm_adj @ x -> sT (rows 0-4 by half0, rows 5-8 by half1;
        //      'i' is used only in ADDRESSES, never to index a register array) ----
        {
            float4 xv[NN];
            #pragma unroll
            for (int j = 0; j < NN; ++j) xv[j] = ld4(&sX[ms][j][c0]);
            #pragma unroll
            for (int ii = 0; ii < 5; ++ii) {
                const int i = ii + half * 5;            // half0: 0-4, half1: 5-9
                if (i < NN) {
                    float4 a = make_float4(0.f, 0.f, 0.f, 0.f);
                    #pragma unroll
                    for (int j = 0; j < NN; ++j) fma4(a, sNA[ms][i * NN + j], xv[j]);
                    st4(&sT[ms][i][c0], a);
                }
            }
        }

        // ---- h = agg @ gcn_W + gcn_b  (k-split across wave halves) ----
        float4 h[NN];
        {
            const float4 z4  = make_float4(0.f, 0.f, 0.f, 0.f);
            const float4 gbv = ld4(&gb[c0]);
            const float4 ini = half ? z4 : gbv;          // bias counted once
            #pragma unroll
            for (int i = 0; i < NN; ++i) h[i] = ini;
            #pragma unroll 2
            for (int kk = 0; kk < 64; kk += 4) {
                const float* wp = gw + (size_t)(k0 + kk) * RR + c0;
                const float4 wv0 = ld4(wp);
                const float4 wv1 = ld4(wp + RR);
                const float4 wv2 = ld4(wp + 2 * RR);
                const float4 wv3 = ld4(wp + 3 * RR);
                #pragma unroll
                for (int i = 0; i < NN; ++i) {
                    const float4 a = ld4(&sT[ms][i][k0 + kk]);  // broadcast per half
                    fma4(h[i], a.x, wv0); fma4(h[i], a.y, wv1);
                    fma4(h[i], a.z, wv2); fma4(h[i], a.w, wv3);
                }
            }
            #pragma unroll
            for (int i = 0; i < NN; ++i) xadd32(h[i]);   // combine k-halves
        }

        // ---- relu + layernorm (reduce across 32 col-lanes; halves identical) ----
        {
            const float4 lgv = ld4(&lg[c0]);
            const float4 lbv = ld4(&lb[c0]);
            #pragma unroll
            for (int i = 0; i < NN; ++i) {
                float4 v = h[i];
                relu4(v);
                float s = v.x + v.y + v.z + v.w;
                float q = v.x*v.x + v.y*v.y + v.z*v.z + v.w*v.w;
                #pragma unroll
                for (int m = 1; m <= 16; m <<= 1) {
                    s += __shfl_xor(s, m);
                    q += __shfl_xor(q, m);
                }
                const float mu  = s * (1.f / RR);
                const float var = q * (1.f / RR) - mu * mu;
                const float rs  = rsqrtf(var + 1e-5f);
                v.x = (v.x - mu) * rs * lgv.x + lbv.x;
                v.y = (v.y - mu) * rs * lgv.y + lbv.y;
                v.z = (v.z - mu) * rs * lgv.z + lbv.z;
                v.w = (v.w - mu) * rs * lgv.w + lbv.w;
                h[i] = v;
            }
        }

        // h_ln -> sX (both halves store identical values; 2-way aliasing is free)
        #pragma unroll
        for (int i = 0; i < NN; ++i) st4(&sX[ms][i][c0], h[i]);

        // residual init: half0 carries h_ln + ffn_b2, half1 carries 0 partials
        {
            const float4 b2v = ld4(&b2[c0]);
            #pragma unroll
            for (int i = 0; i < NN; ++i) {
                if (half) {
                    acc[i] = make_float4(0.f, 0.f, 0.f, 0.f);
                } else {
                    acc[i] = h[i];
                    acc[i].x += b2v.x; acc[i].y += b2v.y;
                    acc[i].z += b2v.z; acc[i].w += b2v.w;
                }
            }
        }

        // ---- FFN: 4 passes over F=512 in 128-wide chunks, k-split ----
        for (int p = 0; p < 4; ++p) {
            const int f0 = p * RR + c0;
            float4 t[NN];
            {
                const float4 z4  = make_float4(0.f, 0.f, 0.f, 0.f);
                const float4 b1v = ld4(&b1[f0]);
                const float4 ini = half ? z4 : b1v;
                #pragma unroll
                for (int i = 0; i < NN; ++i) t[i] = ini;
            }
            #pragma unroll 2
            for (int kk = 0; kk < 64; kk += 4) {
                const float* wp = w1 + (size_t)(k0 + kk) * FF + f0;
                const float4 wv0 = ld4(wp);
                const float4 wv1 = ld4(wp + FF);
                const float4 wv2 = ld4(wp + 2 * FF);
                const float4 wv3 = ld4(wp + 3 * FF);
                #pragma unroll
                for (int i = 0; i < NN; ++i) {
                    const float4 a = ld4(&sX[ms][i][k0 + kk]);
                    fma4(t[i], a.x, wv0); fma4(t[i], a.y, wv1);
                    fma4(t[i], a.z, wv2); fma4(t[i], a.w, wv3);
                }
            }
            #pragma unroll
            for (int i = 0; i < NN; ++i) {
                xadd32(t[i]);            // full pre-activation on both halves
                relu4(t[i]);
                st4(&sT[ms][i][c0], t[i]);   // both halves store (identical)
            }
            #pragma unroll 2
            for (int kk = 0; kk < 64; kk += 4) {
                const float* wp = w2 + (size_t)(p * RR + k0 + kk) * RR + c0;
                const float4 wv0 = ld4(wp);
                const float4 wv1 = ld4(wp + RR);
                const float4 wv2 = ld4(wp + 2 * RR);
                const float4 wv3 = ld4(wp + 3 * RR);
                #pragma unroll
                for (int i = 0; i < NN; ++i) {
                    const float4 a = ld4(&sT[ms][i][k0 + kk]);
                    fma4(acc[i], a.x, wv0); fma4(acc[i], a.y, wv1);
                    fma4(acc[i], a.z, wv2); fma4(acc[i], a.w, wv3);
                }
            }
        }

        // combine k-halves of FFN output (+ residual held in half0)
        #pragma unroll
        for (int i = 0; i < NN; ++i) xadd32(acc[i]);

        // new x for next layer
        if (l + 1 < LL) {
            #pragma unroll
            for (int i = 0; i < NN; ++i) st4(&sX[ms][i][c0], acc[i]);
        }
    }

    // ---- readout: mean over nodes, dot fc_w, sigmoid ----
    {
        const float4 fw = ld4(&fc_w[c0]);
        float4 pv = make_float4(0.f, 0.f, 0.f, 0.f);
        #pragma unroll
        for (int i = 0; i < NN; ++i) {
            pv.x += acc[i].x; pv.y += acc[i].y;
            pv.z += acc[i].z; pv.w += acc[i].w;
        }
        float part = (pv.x*fw.x + pv.y*fw.y + pv.z*fw.z + pv.w*fw.w) * (1.f / 9.f);
        #pragma unroll
        for (int m = 1; m <= 16; m <<= 1) part += __shfl_xor(part, m);
        if (lane == 0) {
            const float yv = part + fc_b[0];
            out[g] = 1.f / (1.f + expf(-yv));
        }
    }
}

extern "C" void kernel_launch(void* const* d_in, const int* in_sizes, int n_in,
                              void* d_out, int out_size, void* d_ws, size_t ws_size,
                              hipStream_t stream) {
    const float* graph     = (const float*)d_in[0];
    const int*   op_idx    = (const int*)  d_in[1];
    const float* op_table  = (const float*)d_in[2];
    const float* dev_embed = (const float*)d_in[3];
    const float* gcn_W     = (const float*)d_in[4];
    const float* gcn_b     = (const float*)d_in[5];
    const float* ln_g      = (const float*)d_in[6];
    const float* ln_b      = (const float*)d_in[7];
    const float* ffn_W1    = (const float*)d_in[8];
    const float* ffn_b1    = (const float*)d_in[9];
    const float* ffn_W2    = (const float*)d_in[10];
    const float* ffn_b2    = (const float*)d_in[11];
    const float* fc_w      = (const float*)d_in[12];
    const float* fc_b      = (const float*)d_in[13];
    float* out = (float*)d_out;

    const int nB = in_sizes[0] / 81;          // 32768
    dim3 grid(nB / GPB), block(256);
    backbone_kernel<<<grid, block, 0, stream>>>(
        graph, op_idx, op_table, dev_embed, gcn_W, gcn_b, ln_g, ln_b,
        ffn_W1, ffn_b1, ffn_W2, ffn_b2, fc_w, fc_b, out);
}

// Round 3
// 2204.191 us; speedup vs baseline: 1.8174x; 1.1761x over previous
//
#include <hip/hip_runtime.h>
#include <math.h>

#define NN 9
#define RR 128
#define FF 512
#define LL 2
#define GPB 4   // graphs per block == waves per block (one 64-lane wave per graph)

__device__ __forceinline__ float4 ld4(const float* p) { return *reinterpret_cast<const float4*>(p); }
__device__ __forceinline__ void st4(float* p, const float4 v) { *reinterpret_cast<float4*>(p) = v; }
__device__ __forceinline__ void fma4(float4& d, const float a, const float4 w) {
    d.x = fmaf(a, w.x, d.x);
    d.y = fmaf(a, w.y, d.y);
    d.z = fmaf(a, w.z, d.z);
    d.w = fmaf(a, w.w, d.w);
}
// combine the two k-halves of a graph (lane ^ 32 within the 64-lane wave)
__device__ __forceinline__ void xadd32(float4& v) {
    v.x += __shfl_xor(v.x, 32);
    v.y += __shfl_xor(v.y, 32);
    v.z += __shfl_xor(v.z, 32);
    v.w += __shfl_xor(v.w, 32);
}
__device__ __forceinline__ void relu4(float4& v) {
    v.x = fmaxf(v.x, 0.f); v.y = fmaxf(v.y, 0.f);
    v.z = fmaxf(v.z, 0.f); v.w = fmaxf(v.w, 0.f);
}

// NOTE: no min-waves arg. (256,4) empirically imposed a 64-VGPR cap on gfx950
// and spilled ~40 float4 register slots to scratch (R1: VGPR 56, R2: VGPR 64,
// WRITE_SIZE ~2 GB). Occupancy here is LDS-limited (38.4 KB -> 4 blocks/CU);
// we just need the allocator free to hold acc/t/h in registers.
__global__ __launch_bounds__(256)
void backbone_kernel(const float* __restrict__ graph,
                     const int*   __restrict__ op_idx,
                     const float* __restrict__ op_table,
                     const float* __restrict__ dev_embed,
                     const float* __restrict__ gcn_W,
                     const float* __restrict__ gcn_b,
                     const float* __restrict__ ln_g,
                     const float* __restrict__ ln_b,
                     const float* __restrict__ ffn_W1,
                     const float* __restrict__ ffn_b1,
                     const float* __restrict__ ffn_W2,
                     const float* __restrict__ ffn_b2,
                     const float* __restrict__ fc_w,
                     const float* __restrict__ fc_b,
                     float* __restrict__ out)
{
    // One wave per graph slot: sX[ms]/sT[ms]/sNA[ms]/sD[ms] are wave-private.
    // No __syncthreads anywhere — in-wave LDS ordering (compiler-inserted
    // lgkmcnt waits on aliasing DS accesses) is sufficient.
    __shared__ float sX[GPB][NN][RR];   // x  / h_ln
    __shared__ float sT[GPB][NN][RR];   // agg / ffn hidden chunk
    __shared__ float sNA[GPB][81];
    __shared__ float sD[GPB][NN];

    const int tid  = threadIdx.x;        // 0..255
    const int lane = tid & 63;           // lane within wave
    const int cg   = tid & 31;           // column group: owns cols 4*cg .. 4*cg+3
    const int half = (tid >> 5) & 1;     // k-half: 0 -> k in [0,64), 1 -> [64,128)
    const int ms   = tid >> 6;           // wave index == graph slot (0..3)
    const int c0   = cg * 4;
    const int k0   = half * 64;
    const int g    = blockIdx.x * GPB + ms;

    // ---- per-wave staging: x = op_table[op_idx] + dev_embed ----
    {
        const float dv0 = dev_embed[lane];
        const float dv1 = dev_embed[lane + 64];
        #pragma unroll
        for (int j = 0; j < NN; ++j) {
            const int idx = op_idx[g * NN + j];          // wave-uniform -> s_load
            sX[ms][j][lane]      = op_table[idx * RR + lane]      + dv0;
            sX[ms][j][lane + 64] = op_table[idx * RR + lane + 64] + dv1;
        }
    }

    // ---- per-wave adjacency normalization (a_hat, rsqrt degrees, norm) ----
    {
        const float* gp = graph + (size_t)g * 81;
        {   // raw a_hat -> sNA (elements 0..63)
            const int i = lane / NN, j = lane - i * NN;
            sNA[ms][lane] = gp[lane] + (i == j ? 1.0f : 0.0f);
        }
        if (lane < 17) {  // elements 64..80
            const int e = lane + 64;
            const int i = e / NN, j = e - i * NN;
            sNA[ms][e] = gp[e] + (i == j ? 1.0f : 0.0f);
        }
        if (lane < NN) {  // row sums -> rsqrt
            float s = 0.f;
            #pragma unroll
            for (int j = 0; j < NN; ++j) s += sNA[ms][lane * NN + j];
            sD[ms][lane] = rsqrtf(s);
        }
        {   // normalize in place
            const int i = lane / NN, j = lane - i * NN;
            sNA[ms][lane] *= sD[ms][i] * sD[ms][j];
        }
        if (lane < 17) {
            const int e = lane + 64;
            const int i = e / NN, j = e - i * NN;
            sNA[ms][e] *= sD[ms][i] * sD[ms][j];
        }
    }

    float4 acc[NN];   // FFN output / final features (compile-time indexed ONLY)

    for (int l = 0; l < LL; ++l) {
        const float* gw = gcn_W  + l * RR * RR;
        const float* gb = gcn_b  + l * RR;
        const float* lg = ln_g   + l * RR;
        const float* lb = ln_b   + l * RR;
        const float* w1 = ffn_W1 + l * RR * FF;
        const float* b1 = ffn_b1 + l * FF;
        const float* w2 = ffn_W2 + l * FF * RR;
        const float* b2 = ffn_b2 + l * RR;

        // ---- agg = norm_adj @ x -> sT (rows 0-4 by half0, rows 5-8 by half1;
        //      'i' is used only in ADDRESSES, never to index a register array) ----
        {
            float4 xv[NN];
            #pragma unroll
            for (int j = 0; j < NN; ++j) xv[j] = ld4(&sX[ms][j][c0]);
            #pragma unroll
            for (int ii = 0; ii < 5; ++ii) {
                const int i = ii + half * 5;            // half0: 0-4, half1: 5-9
                if (i < NN) {
                    float4 a = make_float4(0.f, 0.f, 0.f, 0.f);
                    #pragma unroll
                    for (int j = 0; j < NN; ++j) fma4(a, sNA[ms][i * NN + j], xv[j]);
                    st4(&sT[ms][i][c0], a);
                }
            }
        }

        // ---- h = agg @ gcn_W + gcn_b  (k-split across wave halves) ----
        float4 h[NN];
        {
            const float4 z4  = make_float4(0.f, 0.f, 0.f, 0.f);
            const float4 gbv = ld4(&gb[c0]);
            const float4 ini = half ? z4 : gbv;          // bias counted once
            #pragma unroll
            for (int i = 0; i < NN; ++i) h[i] = ini;
            #pragma unroll 2
            for (int kk = 0; kk < 64; kk += 4) {
                const float* wp = gw + (size_t)(k0 + kk) * RR + c0;
                const float4 wv0 = ld4(wp);
                const float4 wv1 = ld4(wp + RR);
                const float4 wv2 = ld4(wp + 2 * RR);
                const float4 wv3 = ld4(wp + 3 * RR);
                #pragma unroll
                for (int i = 0; i < NN; ++i) {
                    const float4 a = ld4(&sT[ms][i][k0 + kk]);  // broadcast per half
                    fma4(h[i], a.x, wv0); fma4(h[i], a.y, wv1);
                    fma4(h[i], a.z, wv2); fma4(h[i], a.w, wv3);
                }
            }
            #pragma unroll
            for (int i = 0; i < NN; ++i) xadd32(h[i]);   // combine k-halves
        }

        // ---- relu + layernorm (reduce across 32 col-lanes; halves identical) ----
        {
            const float4 lgv = ld4(&lg[c0]);
            const float4 lbv = ld4(&lb[c0]);
            #pragma unroll
            for (int i = 0; i < NN; ++i) {
                float4 v = h[i];
                relu4(v);
                float s = v.x + v.y + v.z + v.w;
                float q = v.x*v.x + v.y*v.y + v.z*v.z + v.w*v.w;
                #pragma unroll
                for (int m = 1; m <= 16; m <<= 1) {
                    s += __shfl_xor(s, m);
                    q += __shfl_xor(q, m);
                }
                const float mu  = s * (1.f / RR);
                const float var = q * (1.f / RR) - mu * mu;
                const float rs  = rsqrtf(var + 1e-5f);
                v.x = (v.x - mu) * rs * lgv.x + lbv.x;
                v.y = (v.y - mu) * rs * lgv.y + lbv.y;
                v.z = (v.z - mu) * rs * lgv.z + lbv.z;
                v.w = (v.w - mu) * rs * lgv.w + lbv.w;
                h[i] = v;
            }
        }

        // h_ln -> sX (both halves store identical values; 2-way aliasing is free)
        #pragma unroll
        for (int i = 0; i < NN; ++i) st4(&sX[ms][i][c0], h[i]);

        // residual init: half0 carries h_ln + ffn_b2, half1 carries 0 partials
        {
            const float4 b2v = ld4(&b2[c0]);
            #pragma unroll
            for (int i = 0; i < NN; ++i) {
                if (half) {
                    acc[i] = make_float4(0.f, 0.f, 0.f, 0.f);
                } else {
                    acc[i] = h[i];
                    acc[i].x += b2v.x; acc[i].y += b2v.y;
                    acc[i].z += b2v.z; acc[i].w += b2v.w;
                }
            }
        }

        // ---- FFN: 4 passes over F=512 in 128-wide chunks, k-split ----
        for (int p = 0; p < 4; ++p) {
            const int f0 = p * RR + c0;
            float4 t[NN];
            {
                const float4 z4  = make_float4(0.f, 0.f, 0.f, 0.f);
                const float4 b1v = ld4(&b1[f0]);
                const float4 ini = half ? z4 : b1v;
                #pragma unroll
                for (int i = 0; i < NN; ++i) t[i] = ini;
            }
            #pragma unroll 2
            for (int kk = 0; kk < 64; kk += 4) {
                const float* wp = w1 + (size_t)(k0 + kk) * FF + f0;
                const float4 wv0 = ld4(wp);
                const float4 wv1 = ld4(wp + FF);
                const float4 wv2 = ld4(wp + 2 * FF);
                const float4 wv3 = ld4(wp + 3 * FF);
                #pragma unroll
                for (int i = 0; i < NN; ++i) {
                    const float4 a = ld4(&sX[ms][i][k0 + kk]);
                    fma4(t[i], a.x, wv0); fma4(t[i], a.y, wv1);
                    fma4(t[i], a.z, wv2); fma4(t[i], a.w, wv3);
                }
            }
            #pragma unroll
            for (int i = 0; i < NN; ++i) {
                xadd32(t[i]);            // full pre-activation on both halves
                relu4(t[i]);
                st4(&sT[ms][i][c0], t[i]);   // both halves store (identical)
            }
            #pragma unroll 2
            for (int kk = 0; kk < 64; kk += 4) {
                const float* wp = w2 + (size_t)(p * RR + k0 + kk) * RR + c0;
                const float4 wv0 = ld4(wp);
                const float4 wv1 = ld4(wp + RR);
                const float4 wv2 = ld4(wp + 2 * RR);
                const float4 wv3 = ld4(wp + 3 * RR);
                #pragma unroll
                for (int i = 0; i < NN; ++i) {
                    const float4 a = ld4(&sT[ms][i][k0 + kk]);
                    fma4(acc[i], a.x, wv0); fma4(acc[i], a.y, wv1);
                    fma4(acc[i], a.z, wv2); fma4(acc[i], a.w, wv3);
                }
            }
        }

        // combine k-halves of FFN output (+ residual held in half0)
        #pragma unroll
        for (int i = 0; i < NN; ++i) xadd32(acc[i]);

        // new x for next layer
        if (l + 1 < LL) {
            #pragma unroll
            for (int i = 0; i < NN; ++i) st4(&sX[ms][i][c0], acc[i]);
        }
    }

    // ---- readout: mean over nodes, dot fc_w, sigmoid ----
    {
        const float4 fw = ld4(&fc_w[c0]);
        float4 pv = make_float4(0.f, 0.f, 0.f, 0.f);
        #pragma unroll
        for (int i = 0; i < NN; ++i) {
            pv.x += acc[i].x; pv.y += acc[i].y;
            pv.z += acc[i].z; pv.w += acc[i].w;
        }
        float part = (pv.x*fw.x + pv.y*fw.y + pv.z*fw.z + pv.w*fw.w) * (1.f / 9.f);
        #pragma unroll
        for (int m = 1; m <= 16; m <<= 1) part += __shfl_xor(part, m);
        if (lane == 0) {
            const float yv = part + fc_b[0];
            out[g] = 1.f / (1.f + expf(-yv));
        }
    }
}

extern "C" void kernel_launch(void* const* d_in, const int* in_sizes, int n_in,
                              void* d_out, int out_size, void* d_ws, size_t ws_size,
                              hipStream_t stream) {
    const float* graph     = (const float*)d_in[0];
    const int*   op_idx    = (const int*)  d_in[1];
    const float* op_table  = (const float*)d_in[2];
    const float* dev_embed = (const float*)d_in[3];
    const float* gcn_W     = (const float*)d_in[4];
    const float* gcn_b     = (const float*)d_in[5];
    const float* ln_g      = (const float*)d_in[6];
    const float* ln_b      = (const float*)d_in[7];
    const float* ffn_W1    = (const float*)d_in[8];
    const float* ffn_b1    = (const float*)d_in[9];
    const float* ffn_W2    = (const float*)d_in[10];
    const float* ffn_b2    = (const float*)d_in[11];
    const float* fc_w      = (const float*)d_in[12];
    const float* fc_b      = (const float*)d_in[13];
    float* out = (float*)d_out;

    const int nB = in_sizes[0] / 81;          // 32768
    dim3 grid(nB / GPB), block(256);
    backbone_kernel<<<grid, block, 0, stream>>>(
        graph, op_idx, op_table, dev_embed, gcn_W, gcn_b, ln_g, ln_b,
        ffn_W1, ffn_b1, ffn_W2, ffn_b2, fc_w, fc_b, out);
}